// Round 3
// baseline (632.078 us; speedup 1.0000x reference)
//
#include <hip/hip_runtime.h>

typedef __attribute__((ext_vector_type(4))) float f32x4;
typedef __attribute__((ext_vector_type(8))) short short8;

// dims: B=8, S=4096, DIN=1024, DH=1024; M=32768, N=2048 (paired-permuted), K=1024
#define NCHUNK 64
#define CLEN 64

__device__ __forceinline__ unsigned short f2bf(float f) {
    union { float f; unsigned int u; } a; a.f = f;
    unsigned int r = a.u + 0x7fffu + ((a.u >> 16) & 1u);   // RTNE (finite)
    return (unsigned short)(r >> 16);
}
__device__ __forceinline__ float bf2f(unsigned short u) {
    union { unsigned int u; float f; } a; a.u = ((unsigned int)u) << 16;
    return a.f;
}

// ---------------- x: f32 -> bf16 (vectorized, grid-stride) ----------------
__global__ __launch_bounds__(256) void conv_bf16(const float* __restrict__ in,
                                                 unsigned short* __restrict__ out, int n4) {
    int stride = gridDim.x * 256;
    for (int i = blockIdx.x * 256 + threadIdx.x; i < n4; i += stride) {
        float4 v = reinterpret_cast<const float4*>(in)[i];
        ushort4 o;
        o.x = f2bf(v.x); o.y = f2bf(v.y); o.z = f2bf(v.z); o.w = f2bf(v.w);
        reinterpret_cast<ushort4*>(out)[i] = o;
    }
}

// ---------------- W: f32 -> bf16 with channel-pair permutation ----------------
// wbP row (nt*256 + i): i<128 -> W row nt*128+i (gate ch), i>=128 -> W row 1024+nt*128+(i-128)
__global__ __launch_bounds__(256) void conv_w_perm(const float* __restrict__ in,
                                                   unsigned short* __restrict__ out) {
    int i = blockIdx.x * 256 + threadIdx.x;       // float4 groups; 524288 total
    int r = i >> 8, c4 = i & 255;                 // W row, 4-col group
    float4 v = reinterpret_cast<const float4*>(in)[i];
    int rp;
    if (r < 1024) { rp = (r >> 7) * 256 + (r & 127); }
    else { int ch = r - 1024; rp = (ch >> 7) * 256 + 128 + (ch & 127); }
    ushort4 o;
    o.x = f2bf(v.x); o.y = f2bf(v.y); o.z = f2bf(v.z); o.w = f2bf(v.w);
    reinterpret_cast<ushort4*>(out)[rp * 256 + c4] = o;
}

// ---------------- GEMM 256x256 tile, BK=32, 3-buffer counted-vmcnt pipeline ----------
// A = xb (M x K bf16), B = wbP (2048 x K bf16, channel-paired). 512 thr = 8 waves (2M x 4N).
// Epilogue: LDS z/g exchange -> packed CV (bf16 c,v) + per-chunk carries (CC,CV f32).
__global__ __launch_bounds__(512, 2) void gemm_fused(
    const unsigned short* __restrict__ xb, const unsigned short* __restrict__ wbP,
    const float* __restrict__ bias,
    unsigned int* __restrict__ CVg, float* __restrict__ CCc, float* __restrict__ CVc)
{
    __shared__ char lds[98304];                   // A: 3x16KB @0, B: 3x16KB @49152
    const int bid = blockIdx.x;
    const int swz = (bid & 7) * 128 + (bid >> 3); // XCD-contiguous logical tiles
    const int nt = swz & 7, mt = swz >> 3;
    const int m0 = mt * 256, chBase = nt * 128, n0p = nt * 256;
    const int t = threadIdx.x;
    const int w = t >> 6, l = t & 63;
    const int wr = (w >> 2) * 128, wc = (w & 3) * 64;

    // staging source (pre-swizzled so linear DMA dest realizes slot = col ^ ((row>>1)&3))
    const int srow = t >> 2;
    const int scol = (t & 3) ^ ((t >> 3) & 3);
    const unsigned short* gA = xb + (size_t)(m0 + srow) * 1024 + scol * 8;
    const unsigned short* gB = wbP + (size_t)(n0p + srow) * 1024 + scol * 8;
    const int sdst = t * 16;

    // fragment LDS byte offsets (read-side swizzle: slot = c16 ^ ((row>>1)&3))
    int offA[8], offB[4];
#pragma unroll
    for (int mi = 0; mi < 8; ++mi) {
        int ar = wr + mi * 16 + (l & 15);
        int sl = (l >> 4) ^ ((ar >> 1) & 3);
        offA[mi] = ar * 64 + sl * 16;
    }
#pragma unroll
    for (int ni = 0; ni < 4; ++ni) {
        int br = wc + ni * 16 + (l & 15);
        int sl = (l >> 4) ^ ((br >> 1) & 3);
        offB[ni] = br * 64 + sl * 16;
    }

    f32x4 acc[8][4];
#pragma unroll
    for (int mi = 0; mi < 8; ++mi)
#pragma unroll
        for (int ni = 0; ni < 4; ++ni) acc[mi][ni] = (f32x4){0.f, 0.f, 0.f, 0.f};

    auto stage = [&](int tile, int buf) {
        const unsigned short* a = gA + tile * 32;
        const unsigned short* b = gB + tile * 32;
        char* dA = lds + buf * 16384 + sdst;
        char* dB = lds + 49152 + buf * 16384 + sdst;
        __builtin_amdgcn_global_load_lds((const __attribute__((address_space(1))) unsigned int*)a,
                                         (__attribute__((address_space(3))) unsigned int*)dA, 16, 0, 0);
        __builtin_amdgcn_global_load_lds((const __attribute__((address_space(1))) unsigned int*)(a + 128 * 1024),
                                         (__attribute__((address_space(3))) unsigned int*)(dA + 8192), 16, 0, 0);
        __builtin_amdgcn_global_load_lds((const __attribute__((address_space(1))) unsigned int*)b,
                                         (__attribute__((address_space(3))) unsigned int*)dB, 16, 0, 0);
        __builtin_amdgcn_global_load_lds((const __attribute__((address_space(1))) unsigned int*)(b + 128 * 1024),
                                         (__attribute__((address_space(3))) unsigned int*)(dB + 8192), 16, 0, 0);
    };

    stage(0, 0); stage(1, 1); stage(2, 2);
    asm volatile("s_waitcnt vmcnt(8)" ::: "memory");   // tile 0 landed (1,2 in flight)
    __builtin_amdgcn_sched_barrier(0);
    __builtin_amdgcn_s_barrier();

    int buf = 0;
    for (int k = 0; k < 32; ++k) {
        const char* bA = lds + buf * 16384;
        const char* bB = lds + 49152 + buf * 16384;
        short8 af[8], bfr[4];
#pragma unroll
        for (int mi = 0; mi < 8; ++mi) af[mi] = *reinterpret_cast<const short8*>(bA + offA[mi]);
#pragma unroll
        for (int ni = 0; ni < 4; ++ni) bfr[ni] = *reinterpret_cast<const short8*>(bB + offB[ni]);
        asm volatile("s_waitcnt lgkmcnt(0)" ::: "memory");  // my ds_reads done
        __builtin_amdgcn_sched_barrier(0);
        __builtin_amdgcn_s_barrier();                        // all waves' reads done -> buf reusable
        if (k < 29) stage(k + 3, buf);                       // (k+3)%3 == k%3
        __builtin_amdgcn_s_setprio(1);
#pragma unroll
        for (int mi = 0; mi < 8; ++mi)
#pragma unroll
            for (int ni = 0; ni < 4; ++ni)
                acc[mi][ni] = __builtin_amdgcn_mfma_f32_16x16x32_bf16(af[mi], bfr[ni], acc[mi][ni], 0, 0, 0);
        __builtin_amdgcn_s_setprio(0);
        if (k <= 28)      asm volatile("s_waitcnt vmcnt(8)" ::: "memory");  // tile k+1 landed
        else if (k == 29) asm volatile("s_waitcnt vmcnt(4)" ::: "memory");
        else if (k == 30) asm volatile("s_waitcnt vmcnt(0)" ::: "memory");
        __builtin_amdgcn_sched_barrier(0);
        __builtin_amdgcn_s_barrier();                        // publish tile k+1
        buf = (buf == 2) ? 0 : buf + 1;
    }

    // ---------- epilogue: activation -> LDS exchange -> packed CV + chunk carries ----------
    const bool isGate = (wc < 128);
    float bv[4];
#pragma unroll
    for (int ni = 0; ni < 4; ++ni) {
        int j = wc + ni * 16 + (l & 15);
        bv[ni] = bias[isGate ? (chBase + j) : (1024 + chBase + (j - 128))];
    }
    const int slotw = (wr != 0);                 // which LDS chunk-slot this wave writes
    for (int p = 0; p < 2; ++p) {
        if (p) __syncthreads();                  // pass-0 reads done before overwrite
#pragma unroll
        for (int mi = 4 * p; mi < 4 * p + 4; ++mi) {
#pragma unroll
            for (int ni = 0; ni < 4; ++ni) {
#pragma unroll
                for (int r = 0; r < 4; ++r) {
                    float v = acc[mi][ni][r] + bv[ni];
                    float o = isGate ? (1.f / (1.f + __expf(-v)))
                                     : ((v >= 0.f) ? (v + 0.5f) : (1.f / (1.f + __expf(-v))));
                    int rr = (mi - 4 * p) * 16 + ((l >> 4) << 2) + r;   // [0,64)
                    int j = wc + ni * 16 + (l & 15);
                    unsigned short* zb = (unsigned short*)lds + slotw * 16384;
                    if (isGate) zb[rr * 128 + j] = f2bf(o);
                    else        zb[8192 + rr * 128 + (j - 128)] = f2bf(o);
                }
            }
        }
        __syncthreads();
        {
            int slot = t >> 8;                   // 0/1 (chunk p / chunk 2+p)
            int tt = t & 255;
            int cglob = (slot ? 2 : 0) + p;
            int mrow0 = m0 + cglob * 64;
            const unsigned short* zb = (const unsigned short*)lds + slot * 16384;
            const unsigned short* gb = zb + 8192;
            int ch = tt & 127, half = tt >> 7;
#pragma unroll 4
            for (int i = 0; i < 32; ++i) {
                int rr = half * 32 + i;
                float z = bf2f(zb[rr * 128 + ch]);
                float gg = bf2f(gb[rr * 128 + ch]);
                unsigned short cb = f2bf(1.f - z);
                unsigned short vb = f2bf(z * gg);
                CVg[(size_t)(mrow0 + rr) * 1024 + chBase + ch] =
                    (unsigned int)cb | ((unsigned int)vb << 16);
            }
            if (tt < 128) {                      // per-channel chunk carry (rounded c,v chain)
                float C = 1.f, V = 0.f;
#pragma unroll 8
                for (int i = 0; i < 64; ++i) {
                    float z = bf2f(zb[i * 128 + tt]);
                    float gg = bf2f(gb[i * 128 + tt]);
                    float c = bf2f(f2bf(1.f - z));
                    float vv = bf2f(f2bf(z * gg));
                    C *= c; V = c * V + vv;
                }
                int b = mrow0 >> 12, ck = (mrow0 >> 6) & 63;
                CCc[(size_t)(b * 64 + ck) * 1024 + chBase + tt] = C;
                CVc[(size_t)(b * 64 + ck) * 1024 + chBase + tt] = V;
            }
        }
    }
}

// ---------------- scan pass 2: sequential scan over 64 chunk carries --------------
__global__ __launch_bounds__(256) void scan_prefix(
    const float* __restrict__ CC, const float* __restrict__ CV,
    const float* __restrict__ h0, float* __restrict__ Hinit)
{
    int g = blockIdx.x * 256 + threadIdx.x;   // 8192 threads
    int h = g & 1023, b = g >> 10;
    float hc = h0[b * 1024 + h];
#pragma unroll 8
    for (int ck = 0; ck < NCHUNK; ++ck) {
        int idx = (b * 64 + ck) * 1024 + h;
        Hinit[idx] = hc;
        hc = CC[idx] * hc + CV[idx];
    }
}

// ---------------- scan pass 3: apply within chunk from packed CV ------------------
__global__ __launch_bounds__(256) void scan_apply(
    const unsigned int* __restrict__ CVg, const float* __restrict__ Hinit,
    float* __restrict__ out)
{
    int g = blockIdx.x * 256 + threadIdx.x;   // 524288
    int ch = g & 1023, ck = (g >> 10) & 63, b = g >> 16;
    int mbase = b * 4096 + ck * CLEN;
    const unsigned int* pc = CVg + (size_t)mbase * 1024 + ch;
    float h = Hinit[g];
    float* po = out + (size_t)mbase * 1024 + ch;
#pragma unroll 8
    for (int i = 0; i < CLEN; ++i) {
        unsigned int u = pc[i * 1024];
        h = bf2f((unsigned short)(u & 0xffff)) * h + bf2f((unsigned short)(u >> 16));
        po[i * 1024] = h;
    }
}

extern "C" void kernel_launch(void* const* d_in, const int* in_sizes, int n_in,
                              void* d_out, int out_size, void* d_ws, size_t ws_size,
                              hipStream_t stream)
{
    const float* x    = (const float*)d_in[0];   // (8,4096,1024)
    const float* h0   = (const float*)d_in[1];   // (8,1,1024)
    const float* W    = (const float*)d_in[2];   // (2048,1024)
    const float* bias = (const float*)d_in[3];   // (2048,)
    float* out = (float*)d_out;

    unsigned short* xb = (unsigned short*)d_out;                    // 67MB staged in d_out
    unsigned short* wbP = (unsigned short*)d_ws;                    // 4MB permuted W bf16
    unsigned int* CVg = (unsigned int*)((char*)d_ws + 4194304);     // 134MB packed (c,v)
    float* CCc   = (float*)((char*)d_ws + 138412032);               // 2MB
    float* CVc   = (float*)((char*)d_ws + 140509184);               // 2MB
    float* Hinit = (float*)((char*)d_ws + 142606336);               // 2MB

    conv_bf16<<<2048, 256, 0, stream>>>(x, xb, 8388608);
    conv_w_perm<<<2048, 256, 0, stream>>>(W, wbP);
    gemm_fused<<<1024, 512, 0, stream>>>(xb, wbP, bias, CVg, CCc, CVc);
    scan_prefix<<<32, 256, 0, stream>>>(CCc, CVc, h0, Hinit);
    scan_apply<<<2048, 256, 0, stream>>>(CVg, Hinit, out);
}